// Round 7
// baseline (5982.562 us; speedup 1.0000x reference)
//
#include <hip/hip_runtime.h>
#include <math.h>
#include <stdint.h>

#define HIDDEN 2048
#define TSTEPS 1024
#define NWG 256
#define TPB 512
#define UPW 8              // hidden units per WG
#define CPT 16             // columns per thread
#define LINE_QW 6          // tagged qwords per producer message
#define LINE_STRIDE_QW 16  // 128 B per producer line (2 parity slots x 8 qwords)
#define GO_STRIDE 32       // ints per go line (128 B)

__device__ __forceinline__ float sigmoidf_(float x) { return 1.0f / (1.0f + __expf(-x)); }

// grid = NWG. Producers publish self-validating tagged lines (no ack, no flag).
// WG 255's wave 7 is the watcher: polls all 256 lines (1 poller/line), assembles
// h_{s+1}, writes it to hhist (fresh address), acks once, fans out go.
__global__ __launch_bounds__(TPB, 2)
void lstm_hist(const float* __restrict__ features,
               const float* __restrict__ pc,
               const float* __restrict__ W_ih,
               const float* __restrict__ W_hh,
               const float* __restrict__ b_ih,
               const float* __restrict__ b_hh,
               const float* __restrict__ W_fc,
               const float* __restrict__ b_fc,
               float* __restrict__ out,
               uint64_t* __restrict__ msg,   // NWG lines x LINE_STRIDE_QW qwords, memset 0
               int*      __restrict__ go,    // 64 lines x GO_STRIDE ints, memset 0
               float*    __restrict__ hhist) // (TSTEPS+1)*HIDDEN floats, slot s = h_s
{
    const int b    = blockIdx.x;
    const int t    = threadIdx.x;
    const int lane = t & 63;
    const int wave = t >> 6;

    // Invalidate L1/L2 so plain cached reads of hhist can't see stale lines
    // from a previous graph replay.
    __builtin_amdgcn_fence(__ATOMIC_ACQUIRE, "agent");

    const int g    = t & 3;        // gate block 0..3 (i,f,g,o)
    const int cc   = t >> 2;       // column-chunk 0..127
    const int col0 = cc * CPT;

    __shared__ float pc_sh[2 * TSTEPS];
    __shared__ float red[8 * 32];
    __shared__ float outred[16];

    {   // point cloud -> LDS
        const float4* p4 = reinterpret_cast<const float4*>(pc);
        reinterpret_cast<float4*>(pc_sh)[t] = p4[t];
    }

    // W_hh slice -> registers: w[ji][k] = W_hh[g*2048 + b*8 + ji][col0 + k]
    float w[UPW][CPT];
    {
        const int baserow = g * HIDDEN + b * UPW;
        #pragma unroll
        for (int ji = 0; ji < UPW; ++ji) {
            const float4* src = reinterpret_cast<const float4*>(
                W_hh + (size_t)(baserow + ji) * HIDDEN + col0);
            float4 a0 = src[0], a1 = src[1], a2 = src[2], a3 = src[3];
            w[ji][0]  = a0.x; w[ji][1]  = a0.y; w[ji][2]  = a0.z; w[ji][3]  = a0.w;
            w[ji][4]  = a1.x; w[ji][5]  = a1.y; w[ji][6]  = a1.z; w[ji][7]  = a1.w;
            w[ji][8]  = a2.x; w[ji][9]  = a2.y; w[ji][10] = a2.z; w[ji][11] = a2.w;
            w[ji][12] = a3.x; w[ji][13] = a3.y; w[ji][14] = a3.z; w[ji][15] = a3.w;
        }
    }

    // per-row constants + cell state for wave 0 (row id l = lane&31: gate = l>>3, unit = l&7)
    float bias_r = 0.0f, wi0_r = 0.0f, wi1_r = 0.0f, creg = 0.0f;
    if (wave == 0) {
        const int l   = lane & 31;
        const int row = (l >> 3) * HIDDEN + b * UPW + (l & 7);
        bias_r = b_ih[row] + b_hh[row];
        wi0_r  = W_ih[row * 2 + 0];
        wi1_r  = W_ih[row * 2 + 1];
    }
    __syncthreads();

    // ---- recurrence ----
    for (int s = 0; s < TSTEPS; ++s) {
        const int rot = (s >= 1) && (b == ((s - 1) & 255));   // this WG emits out[s-1]
        const float* hsrc = (s == 0) ? features : (hhist + (size_t)s * HIDDEN);

        // h slice via plain cached loads (fresh address every step)
        float hr[CPT];
        #pragma unroll
        for (int k = 0; k < CPT; k += 4) {
            float4 hv = *reinterpret_cast<const float4*>(hsrc + col0 + k);
            hr[k] = hv.x; hr[k + 1] = hv.y; hr[k + 2] = hv.z; hr[k + 3] = hv.w;
        }

        // FMA phase
        float acc[UPW];
        #pragma unroll
        for (int ji = 0; ji < UPW; ++ji) acc[ji] = 0.0f;
        #pragma unroll
        for (int k = 0; k < CPT; ++k) {
            #pragma unroll
            for (int ji = 0; ji < UPW; ++ji) acc[ji] += w[ji][k] * hr[k];
        }
        #pragma unroll
        for (int m = 4; m < 64; m <<= 1) {
            #pragma unroll
            for (int ji = 0; ji < UPW; ++ji) acc[ji] += __shfl_xor(acc[ji], m);
        }
        if (lane < 4) {
            #pragma unroll
            for (int ji = 0; ji < UPW; ++ji) red[wave * 32 + lane * 8 + ji] = acc[ji];
        }

        // fc partials for out[s-1] from registers (rotating WG; rides barrier (a))
        if (rot) {
            float po0 = 0.0f, po1 = 0.0f;
            #pragma unroll
            for (int k = 0; k < CPT; ++k) {
                po0 += hr[k] * W_fc[col0 + k];
                po1 += hr[k] * W_fc[HIDDEN + col0 + k];
            }
            #pragma unroll
            for (int m = 1; m < 64; m <<= 1) {
                po0 += __shfl_xor(po0, m);
                po1 += __shfl_xor(po1, m);
            }
            if (lane == 0) { outred[wave * 2 + 0] = po0; outred[wave * 2 + 1] = po1; }
        }
        __syncthreads();   // (a) red[] + outred[] ready

        const int par = ((s + 1) & 1) * 8;   // parity slot offset (qwords)

        if (wave == 0) {
            // final reduce + gates
            const int l = lane & 31;
            float sum = 0.0f;
            #pragma unroll
            for (int ww = 0; ww < 8; ++ww) sum += red[ww * 32 + l];
            const float x0 = pc_sh[2 * s], x1 = pc_sh[2 * s + 1];
            const float gate = sum + bias_r + wi0_r * x0 + wi1_r * x1;
            const float iv = __shfl(gate, (lane & 7));
            const float fv = __shfl(gate, 8 + (lane & 7));
            const float gv = __shfl(gate, 16 + (lane & 7));
            const float ov = __shfl(gate, 24 + (lane & 7));
            const float cnew = sigmoidf_(fv) * creg + sigmoidf_(iv) * tanhf(gv);
            const float hnew = sigmoidf_(ov) * tanhf(cnew);
            creg = cnew;   // lane tracks unit lane&7
            const uint32_t hb = __float_as_uint(hnew);

            // self-validating publish: 6 tagged qwords, NO ack, NO separate flag.
            // qword l: [tag16 | half(3l) | half(3l+1) | half(3l+2)],
            // half m: (m&1)? hi16 : lo16 of float m>>1.
            uint64_t v = ((uint64_t)(uint32_t)(s + 1)) << 48;
            #pragma unroll
            for (int i = 0; i < 3; ++i) {
                const int m  = 3 * lane + i;
                const int mc = (m < 16) ? m : 15;
                const uint32_t bits = __shfl(hb, mc >> 1);   // unit mc>>1 lives at lane mc>>1
                const uint32_t half = (mc & 1) ? (bits >> 16) : (bits & 0xFFFFu);
                if (m < 16) v |= (uint64_t)half << (32 - 16 * i);
            }
            if (lane < LINE_QW) {
                __hip_atomic_store(msg + (size_t)b * LINE_STRIDE_QW + par + lane,
                                   v, __ATOMIC_RELAXED, __HIP_MEMORY_SCOPE_AGENT);
            }
        }

        // ---- watcher: WG 255 wave 7 (idle after (a); overlaps all gate compute) ----
        if (b == NWG - 1 && wave == 7) {
            const int l4 = lane * 4;
            const uint32_t tagexp = (uint32_t)(s + 1);
            uint64_t q[4][LINE_QW];
            for (;;) {
                #pragma unroll
                for (int i = 0; i < 4; ++i) {
                    const uint64_t* lp = msg + (size_t)(l4 + i) * LINE_STRIDE_QW + par;
                    #pragma unroll
                    for (int j = 0; j < LINE_QW; ++j) {
                        q[i][j] = __hip_atomic_load(lp + j, __ATOMIC_RELAXED,
                                                    __HIP_MEMORY_SCOPE_AGENT);
                    }
                }
                bool ok = true;
                #pragma unroll
                for (int i = 0; i < 4; ++i) {
                    #pragma unroll
                    for (int j = 0; j < LINE_QW; ++j) {
                        ok &= ((uint32_t)(q[i][j] >> 48) == tagexp);
                    }
                }
                if (ok) break;
            }
            // assemble h_{s+1} and write to hhist (agent-scope: IF-visible for cached fills)
            uint64_t* hq = reinterpret_cast<uint64_t*>(hhist + (size_t)(s + 1) * HIDDEN);
            #pragma unroll
            for (int i = 0; i < 4; ++i) {
                uint32_t H[18];
                #pragma unroll
                for (int j = 0; j < LINE_QW; ++j) {
                    H[3 * j + 0] = (uint32_t)(q[i][j] >> 32) & 0xFFFFu;
                    H[3 * j + 1] = (uint32_t)(q[i][j] >> 16) & 0xFFFFu;
                    H[3 * j + 2] = (uint32_t)(q[i][j] >>  0) & 0xFFFFu;
                }
                #pragma unroll
                for (int k = 0; k < 4; ++k) {
                    const uint32_t f0 = H[4 * k + 0] | (H[4 * k + 1] << 16);
                    const uint32_t f1 = H[4 * k + 2] | (H[4 * k + 3] << 16);
                    __hip_atomic_store(hq + (size_t)(l4 + i) * 4 + k,
                                       (uint64_t)f0 | ((uint64_t)f1 << 32),
                                       __ATOMIC_RELAXED, __HIP_MEMORY_SCOPE_AGENT);
                }
            }
            // single ack: h data at the coherence point before go becomes visible
            asm volatile("s_waitcnt vmcnt(0)" ::: "memory");
            __hip_atomic_store(go + (size_t)lane * GO_STRIDE, s + 1,
                               __ATOMIC_RELAXED, __HIP_MEMORY_SCOPE_AGENT);
        }

        // out[s-1] final sum (outred valid since (a))
        if (rot && t == 64) {
            float o0 = 0.0f, o1 = 0.0f;
            #pragma unroll
            for (int ww = 0; ww < 8; ++ww) { o0 += outred[ww * 2]; o1 += outred[ww * 2 + 1]; }
            out[(s - 1) * 2 + 0] = 0.25f * o0 + b_fc[0];
            out[(s - 1) * 2 + 1] = 0.25f * o1 + b_fc[1];
        }

        // wait for go (<=4 pollers/line, busy spin). WG 255: its own wave 7 already
        // detected + acked; __syncthreads orders it for the whole WG.
        if (t == 0 && b != NWG - 1) {
            const int* gop = go + (size_t)(b >> 2) * GO_STRIDE;
            while (__hip_atomic_load(gop, __ATOMIC_RELAXED,
                                     __HIP_MEMORY_SCOPE_AGENT) < s + 1) {}
        }
        __syncthreads();   // (b) h_{s+1} at IF; cached loads safe
    }

    // ---- epilogue: out[T-1] = fc(h_T) ----
    if (b == ((TSTEPS - 1) & 255)) {
        const float* hsrc = hhist + (size_t)TSTEPS * HIDDEN;
        float po0 = 0.0f, po1 = 0.0f;
        #pragma unroll
        for (int k = 0; k < CPT; ++k) {
            const float hv = hsrc[col0 + k];
            po0 += hv * W_fc[col0 + k];
            po1 += hv * W_fc[HIDDEN + col0 + k];
        }
        #pragma unroll
        for (int m = 1; m < 64; m <<= 1) {
            po0 += __shfl_xor(po0, m);
            po1 += __shfl_xor(po1, m);
        }
        if (lane == 0) { outred[wave * 2 + 0] = po0; outred[wave * 2 + 1] = po1; }
        __syncthreads();
        if (t == 0) {
            float o0 = 0.0f, o1 = 0.0f;
            #pragma unroll
            for (int ww = 0; ww < 8; ++ww) { o0 += outred[ww * 2]; o1 += outred[ww * 2 + 1]; }
            out[(TSTEPS - 1) * 2 + 0] = 0.25f * o0 + b_fc[0];
            out[(TSTEPS - 1) * 2 + 1] = 0.25f * o1 + b_fc[1];
        }
    }
}

extern "C" void kernel_launch(void* const* d_in, const int* in_sizes, int n_in,
                              void* d_out, int out_size, void* d_ws, size_t ws_size,
                              hipStream_t stream) {
    const float* features = (const float*)d_in[0];
    const float* pc       = (const float*)d_in[1];
    const float* W_ih     = (const float*)d_in[2];
    const float* W_hh     = (const float*)d_in[3];
    const float* b_ih     = (const float*)d_in[4];
    const float* b_hh     = (const float*)d_in[5];
    const float* W_fc     = (const float*)d_in[6];
    const float* b_fc     = (const float*)d_in[7];
    float* out = (float*)d_out;

    const size_t msg_bytes = (size_t)NWG * LINE_STRIDE_QW * sizeof(uint64_t);  // 32 KB
    const size_t go_bytes  = (size_t)64 * GO_STRIDE * sizeof(int);             //  8 KB
    const size_t hh_off    = msg_bytes + go_bytes;                             // 40 KB

    uint64_t* msg   = (uint64_t*)d_ws;
    int*      go    = (int*)((char*)d_ws + msg_bytes);
    float*    hhist = (float*)((char*)d_ws + hh_off);

    // tags/go must start at 0 every call (graph replays don't re-poison ws)
    hipMemsetAsync(d_ws, 0, hh_off, stream);

    hipLaunchKernelGGL(lstm_hist, dim3(NWG), dim3(TPB), 0, stream,
                       features, pc, W_ih, W_hh, b_ih, b_hh, W_fc, b_fc,
                       out, msg, go, hhist);
}

// Round 8
// 3704.540 us; speedup vs baseline: 1.6149x; 1.6149x over previous
//
#include <hip/hip_runtime.h>
#include <math.h>
#include <stdint.h>

#define HIDDEN 2048
#define TSTEPS 1024
#define NWG 256
#define TPB 512
#define UPW 8              // hidden units per WG
#define CPT 16             // columns per thread
#define CHUNK_QW 6         // tagged qwords per producer chunk (16 halves + tags)
#define STEP_QW (NWG * CHUNK_QW)   // 1536 qwords per step slot
#define GO_STRIDE 32       // ints per go line (128 B)
#define FLAG_STRIDE 32

__device__ __forceinline__ float sigmoidf_(float x) { return 1.0f / (1.0f + __expf(-x)); }

// ===================== primary (round-8): tagged h, no acks anywhere =====================
// Producers publish h as 6 self-validating tagged qwords at a per-step fresh address.
// WG 255 wave 7 (idle during gate compute) polls qword 5 of all 256 chunks
// (4 loads/lane/round), then fans out go. Consumers gated by go, validate all
// 12 tags of their slice on the cached read; rare agent-scope retry as backstop.
__global__ __launch_bounds__(TPB, 2)
void lstm_v8(const float* __restrict__ features,
             const float* __restrict__ pc,
             const float* __restrict__ W_ih,
             const float* __restrict__ W_hh,
             const float* __restrict__ b_ih,
             const float* __restrict__ b_hh,
             const float* __restrict__ W_fc,
             const float* __restrict__ b_fc,
             float* __restrict__ out,
             int*      __restrict__ go,   // 64 lines x GO_STRIDE ints, memset 0
             uint64_t* __restrict__ hh)   // (TSTEPS+1)*STEP_QW qwords, memset 0
{
    const int b    = blockIdx.x;
    const int t    = threadIdx.x;
    const int lane = t & 63;
    const int wave = t >> 6;
    const int g    = t & 3;        // gate block 0..3 (i,f,g,o)
    const int cc   = t >> 2;       // column-chunk 0..127
    const int col0 = cc * CPT;

    // Invalidate L1/L2 across graph replays before any cached read of ws.
    __builtin_amdgcn_fence(__ATOMIC_ACQUIRE, "agent");

    __shared__ float pc_sh[2 * TSTEPS];
    __shared__ float red[8 * 32];
    __shared__ float outred[16];

    {   // point cloud -> LDS
        const float4* p4 = reinterpret_cast<const float4*>(pc);
        reinterpret_cast<float4*>(pc_sh)[t] = p4[t];
    }

    // W_hh slice -> registers
    float w[UPW][CPT];
    {
        const int baserow = g * HIDDEN + b * UPW;
        #pragma unroll
        for (int ji = 0; ji < UPW; ++ji) {
            const float4* src = reinterpret_cast<const float4*>(
                W_hh + (size_t)(baserow + ji) * HIDDEN + col0);
            float4 a0 = src[0], a1 = src[1], a2 = src[2], a3 = src[3];
            w[ji][0]  = a0.x; w[ji][1]  = a0.y; w[ji][2]  = a0.z; w[ji][3]  = a0.w;
            w[ji][4]  = a1.x; w[ji][5]  = a1.y; w[ji][6]  = a1.z; w[ji][7]  = a1.w;
            w[ji][8]  = a2.x; w[ji][9]  = a2.y; w[ji][10] = a2.z; w[ji][11] = a2.w;
            w[ji][12] = a3.x; w[ji][13] = a3.y; w[ji][14] = a3.z; w[ji][15] = a3.w;
        }
    }

    float bias_r = 0.0f, wi0_r = 0.0f, wi1_r = 0.0f, creg = 0.0f;
    if (wave == 0) {
        const int l   = lane & 31;
        const int row = (l >> 3) * HIDDEN + b * UPW + (l & 7);
        bias_r = b_ih[row] + b_hh[row];
        wi0_r  = W_ih[row * 2 + 0];
        wi1_r  = W_ih[row * 2 + 1];
    }
    __syncthreads();

    for (int s = 0; s < TSTEPS; ++s) {
        const int rot = (s >= 1) && (b == ((s - 1) & 255));

        // ---- load h_s slice ----
        float hr[CPT];
        if (s == 0) {
            #pragma unroll
            for (int k = 0; k < CPT; k += 4) {
                float4 hv = *reinterpret_cast<const float4*>(features + col0 + k);
                hr[k] = hv.x; hr[k + 1] = hv.y; hr[k + 2] = hv.z; hr[k + 3] = hv.w;
            }
        } else {
            const uint64_t* qp = hh + (size_t)s * STEP_QW + (size_t)(cc * 2) * CHUNK_QW;
            const uint32_t tagexp = (uint32_t)s;
            #pragma unroll
            for (int c2 = 0; c2 < 2; ++c2) {
                uint64_t q[CHUNK_QW];
                const ulonglong2* qp2 = reinterpret_cast<const ulonglong2*>(qp + c2 * CHUNK_QW);
                ulonglong2 u0 = qp2[0], u1 = qp2[1], u2 = qp2[2];
                q[0] = u0.x; q[1] = u0.y; q[2] = u1.x;
                q[3] = u1.y; q[4] = u2.x; q[5] = u2.y;
                // validate tags; rare agent-scope retry (race backstop)
                #pragma unroll
                for (int j = 0; j < CHUNK_QW; ++j) {
                    if ((uint32_t)(q[j] >> 48) != tagexp) {
                        do {
                            q[j] = __hip_atomic_load(qp + c2 * CHUNK_QW + j,
                                                     __ATOMIC_RELAXED, __HIP_MEMORY_SCOPE_AGENT);
                        } while ((uint32_t)(q[j] >> 48) != tagexp);
                    }
                }
                uint32_t H[3 * CHUNK_QW];
                #pragma unroll
                for (int j = 0; j < CHUNK_QW; ++j) {
                    H[3 * j + 0] = (uint32_t)(q[j] >> 32) & 0xFFFFu;
                    H[3 * j + 1] = (uint32_t)(q[j] >> 16) & 0xFFFFu;
                    H[3 * j + 2] = (uint32_t)(q[j] >>  0) & 0xFFFFu;
                }
                #pragma unroll
                for (int i = 0; i < 8; ++i) {
                    hr[c2 * 8 + i] = __uint_as_float(H[2 * i] | (H[2 * i + 1] << 16));
                }
            }
        }

        // ---- FMA phase ----
        float acc[UPW];
        #pragma unroll
        for (int ji = 0; ji < UPW; ++ji) acc[ji] = 0.0f;
        #pragma unroll
        for (int k = 0; k < CPT; ++k) {
            #pragma unroll
            for (int ji = 0; ji < UPW; ++ji) acc[ji] += w[ji][k] * hr[k];
        }
        #pragma unroll
        for (int m = 4; m < 64; m <<= 1) {
            #pragma unroll
            for (int ji = 0; ji < UPW; ++ji) acc[ji] += __shfl_xor(acc[ji], m);
        }
        if (lane < 4) {
            #pragma unroll
            for (int ji = 0; ji < UPW; ++ji) red[wave * 32 + lane * 8 + ji] = acc[ji];
        }

        // fc partials for out[s-1] (rotating WG; rides barrier (a))
        if (rot) {
            float po0 = 0.0f, po1 = 0.0f;
            #pragma unroll
            for (int k = 0; k < CPT; ++k) {
                po0 += hr[k] * W_fc[col0 + k];
                po1 += hr[k] * W_fc[HIDDEN + col0 + k];
            }
            #pragma unroll
            for (int m = 1; m < 64; m <<= 1) {
                po0 += __shfl_xor(po0, m);
                po1 += __shfl_xor(po1, m);
            }
            if (lane == 0) { outred[wave * 2 + 0] = po0; outred[wave * 2 + 1] = po1; }
        }
        __syncthreads();   // (a) red[] + outred[] ready

        const size_t pubbase = (size_t)(s + 1) * STEP_QW;

        if (wave == 0) {
            // final reduce + gates
            const int l = lane & 31;
            float sum = 0.0f;
            #pragma unroll
            for (int ww = 0; ww < 8; ++ww) sum += red[ww * 32 + l];
            const float x0 = pc_sh[2 * s], x1 = pc_sh[2 * s + 1];
            const float gate = sum + bias_r + wi0_r * x0 + wi1_r * x1;
            const float iv = __shfl(gate, (lane & 7));
            const float fv = __shfl(gate, 8 + (lane & 7));
            const float gv = __shfl(gate, 16 + (lane & 7));
            const float ov = __shfl(gate, 24 + (lane & 7));
            const float cnew = sigmoidf_(fv) * creg + sigmoidf_(iv) * tanhf(gv);
            const float hnew = sigmoidf_(ov) * tanhf(cnew);
            creg = cnew;   // lane tracks unit lane&7
            const uint32_t hb = __float_as_uint(hnew);

            // self-validating publish: 6 tagged qwords, NO ack, NO flag.
            // qword l: [tag16 | half(3l) | half(3l+1) | half(3l+2)],
            // half m = (m&1)? hi16 : lo16 of float m>>1 (r3-validated packing).
            uint64_t v = ((uint64_t)(uint32_t)(s + 1)) << 48;
            #pragma unroll
            for (int i = 0; i < 3; ++i) {
                const int m  = 3 * lane + i;
                const int mc = (m < 16) ? m : 15;
                const uint32_t bits = __shfl(hb, mc >> 1);
                const uint32_t half = (mc & 1) ? (bits >> 16) : (bits & 0xFFFFu);
                if (m < 16) v |= (uint64_t)half << (32 - 16 * i);
            }
            if (lane < CHUNK_QW) {
                __hip_atomic_store(hh + pubbase + (size_t)b * CHUNK_QW + lane,
                                   v, __ATOMIC_RELAXED, __HIP_MEMORY_SCOPE_AGENT);
            }
        }

        // ---- watcher: WG 255 wave 7, overlaps all gate compute; 4 loads/lane/round ----
        if (b == NWG - 1 && wave == 7) {
            const uint32_t tagexp = (uint32_t)(s + 1);
            const int l4 = lane * 4;
            const uint64_t* p0 = hh + pubbase + (size_t)(l4 + 0) * CHUNK_QW + 5;
            const uint64_t* p1 = hh + pubbase + (size_t)(l4 + 1) * CHUNK_QW + 5;
            const uint64_t* p2 = hh + pubbase + (size_t)(l4 + 2) * CHUNK_QW + 5;
            const uint64_t* p3 = hh + pubbase + (size_t)(l4 + 3) * CHUNK_QW + 5;
            for (;;) {
                const uint64_t q0 = __hip_atomic_load(p0, __ATOMIC_RELAXED, __HIP_MEMORY_SCOPE_AGENT);
                const uint64_t q1 = __hip_atomic_load(p1, __ATOMIC_RELAXED, __HIP_MEMORY_SCOPE_AGENT);
                const uint64_t q2 = __hip_atomic_load(p2, __ATOMIC_RELAXED, __HIP_MEMORY_SCOPE_AGENT);
                const uint64_t q3 = __hip_atomic_load(p3, __ATOMIC_RELAXED, __HIP_MEMORY_SCOPE_AGENT);
                const bool ok = ((uint32_t)(q0 >> 48) == tagexp) &
                                ((uint32_t)(q1 >> 48) == tagexp) &
                                ((uint32_t)(q2 >> 48) == tagexp) &
                                ((uint32_t)(q3 >> 48) == tagexp);
                if (__all(ok)) break;
            }
            __hip_atomic_store(go + (size_t)lane * GO_STRIDE, s + 1,
                               __ATOMIC_RELAXED, __HIP_MEMORY_SCOPE_AGENT);
        }

        // out[s-1] final sum
        if (rot && t == 64) {
            float o0 = 0.0f, o1 = 0.0f;
            #pragma unroll
            for (int ww = 0; ww < 8; ++ww) { o0 += outred[ww * 2]; o1 += outred[ww * 2 + 1]; }
            out[(s - 1) * 2 + 0] = 0.25f * o0 + b_fc[0];
            out[(s - 1) * 2 + 1] = 0.25f * o1 + b_fc[1];
        }

        // go gate (<=4 pollers/line, busy spin); WG 255 gated by its own wave 7
        if (t == 0 && b != NWG - 1) {
            const int* gop = go + (size_t)(b >> 2) * GO_STRIDE;
            while (__hip_atomic_load(gop, __ATOMIC_RELAXED,
                                     __HIP_MEMORY_SCOPE_AGENT) < s + 1) {}
        }
        __syncthreads();   // (b)
    }

    // ---- epilogue: out[T-1] = fc(h_T); (T-1)&255 = 255 ----
    if (b == NWG - 1) {
        const uint64_t* qp = hh + (size_t)TSTEPS * STEP_QW + (size_t)(cc * 2) * CHUNK_QW;
        const uint32_t tagexp = (uint32_t)TSTEPS;
        float hv[CPT];
        #pragma unroll
        for (int c2 = 0; c2 < 2; ++c2) {
            uint64_t q[CHUNK_QW];
            const ulonglong2* qp2 = reinterpret_cast<const ulonglong2*>(qp + c2 * CHUNK_QW);
            ulonglong2 u0 = qp2[0], u1 = qp2[1], u2 = qp2[2];
            q[0] = u0.x; q[1] = u0.y; q[2] = u1.x;
            q[3] = u1.y; q[4] = u2.x; q[5] = u2.y;
            #pragma unroll
            for (int j = 0; j < CHUNK_QW; ++j) {
                if ((uint32_t)(q[j] >> 48) != tagexp) {
                    do {
                        q[j] = __hip_atomic_load(qp + c2 * CHUNK_QW + j,
                                                 __ATOMIC_RELAXED, __HIP_MEMORY_SCOPE_AGENT);
                    } while ((uint32_t)(q[j] >> 48) != tagexp);
                }
            }
            uint32_t H[3 * CHUNK_QW];
            #pragma unroll
            for (int j = 0; j < CHUNK_QW; ++j) {
                H[3 * j + 0] = (uint32_t)(q[j] >> 32) & 0xFFFFu;
                H[3 * j + 1] = (uint32_t)(q[j] >> 16) & 0xFFFFu;
                H[3 * j + 2] = (uint32_t)(q[j] >>  0) & 0xFFFFu;
            }
            #pragma unroll
            for (int i = 0; i < 8; ++i) {
                hv[c2 * 8 + i] = __uint_as_float(H[2 * i] | (H[2 * i + 1] << 16));
            }
        }
        float po0 = 0.0f, po1 = 0.0f;
        #pragma unroll
        for (int k = 0; k < CPT; ++k) {
            po0 += hv[k] * W_fc[col0 + k];
            po1 += hv[k] * W_fc[HIDDEN + col0 + k];
        }
        #pragma unroll
        for (int m = 1; m < 64; m <<= 1) {
            po0 += __shfl_xor(po0, m);
            po1 += __shfl_xor(po1, m);
        }
        if (lane == 0) { outred[wave * 2 + 0] = po0; outred[wave * 2 + 1] = po1; }
        __syncthreads();
        if (t == 0) {
            float o0 = 0.0f, o1 = 0.0f;
            #pragma unroll
            for (int ww = 0; ww < 8; ++ww) { o0 += outred[ww * 2]; o1 += outred[ww * 2 + 1]; }
            out[(TSTEPS - 1) * 2 + 0] = 0.25f * o0 + b_fc[0];
            out[(TSTEPS - 1) * 2 + 1] = 0.25f * o1 + b_fc[1];
        }
    }
}

// ===================== fallback: exact round-6 kernel (3595 us, needs ~8.5 MB) =====================
__global__ __launch_bounds__(TPB, 2)
void lstm_v6(const float* __restrict__ features,
             const float* __restrict__ pc,
             const float* __restrict__ W_ih,
             const float* __restrict__ W_hh,
             const float* __restrict__ b_ih,
             const float* __restrict__ b_hh,
             const float* __restrict__ W_fc,
             const float* __restrict__ b_fc,
             float* __restrict__ out,
             int*   __restrict__ flags,
             int*   __restrict__ go,
             float* __restrict__ hhist)
{
    const int b    = blockIdx.x;
    const int t    = threadIdx.x;
    const int lane = t & 63;
    const int wave = t >> 6;
    __builtin_amdgcn_fence(__ATOMIC_ACQUIRE, "agent");
    const int g    = t & 3;
    const int cc   = t >> 2;
    const int col0 = cc * CPT;
    const bool watcher = (b == NWG - 1) && (wave == 0);

    __shared__ float pc_sh[2 * TSTEPS];
    __shared__ float red[8 * 32];
    __shared__ float outred[16];

    {
        const float4* p4 = reinterpret_cast<const float4*>(pc);
        reinterpret_cast<float4*>(pc_sh)[t] = p4[t];
    }
    float w[UPW][CPT];
    {
        const int baserow = g * HIDDEN + b * UPW;
        #pragma unroll
        for (int ji = 0; ji < UPW; ++ji) {
            const float4* src = reinterpret_cast<const float4*>(
                W_hh + (size_t)(baserow + ji) * HIDDEN + col0);
            float4 a0 = src[0], a1 = src[1], a2 = src[2], a3 = src[3];
            w[ji][0]  = a0.x; w[ji][1]  = a0.y; w[ji][2]  = a0.z; w[ji][3]  = a0.w;
            w[ji][4]  = a1.x; w[ji][5]  = a1.y; w[ji][6]  = a1.z; w[ji][7]  = a1.w;
            w[ji][8]  = a2.x; w[ji][9]  = a2.y; w[ji][10] = a2.z; w[ji][11] = a2.w;
            w[ji][12] = a3.x; w[ji][13] = a3.y; w[ji][14] = a3.z; w[ji][15] = a3.w;
        }
    }
    float bias_r = 0.0f, wi0_r = 0.0f, wi1_r = 0.0f, creg = 0.0f;
    if (wave == 0) {
        const int l   = lane & 31;
        const int row = (l >> 3) * HIDDEN + b * UPW + (l & 7);
        bias_r = b_ih[row] + b_hh[row];
        wi0_r  = W_ih[row * 2 + 0];
        wi1_r  = W_ih[row * 2 + 1];
    }
    __syncthreads();

    for (int s = 0; s < TSTEPS; ++s) {
        const int rot = (s >= 1) && (b == ((s - 1) & 255));
        const float* hsrc = (s == 0) ? features : (hhist + (size_t)s * HIDDEN);
        float hr[CPT];
        #pragma unroll
        for (int k = 0; k < CPT; k += 4) {
            float4 hv = *reinterpret_cast<const float4*>(hsrc + col0 + k);
            hr[k] = hv.x; hr[k + 1] = hv.y; hr[k + 2] = hv.z; hr[k + 3] = hv.w;
        }
        float acc[UPW];
        #pragma unroll
        for (int ji = 0; ji < UPW; ++ji) acc[ji] = 0.0f;
        #pragma unroll
        for (int k = 0; k < CPT; ++k) {
            #pragma unroll
            for (int ji = 0; ji < UPW; ++ji) acc[ji] += w[ji][k] * hr[k];
        }
        #pragma unroll
        for (int m = 4; m < 64; m <<= 1) {
            #pragma unroll
            for (int ji = 0; ji < UPW; ++ji) acc[ji] += __shfl_xor(acc[ji], m);
        }
        if (lane < 4) {
            #pragma unroll
            for (int ji = 0; ji < UPW; ++ji) red[wave * 32 + lane * 8 + ji] = acc[ji];
        }
        if (rot) {
            float po0 = 0.0f, po1 = 0.0f;
            #pragma unroll
            for (int k = 0; k < CPT; ++k) {
                po0 += hr[k] * W_fc[col0 + k];
                po1 += hr[k] * W_fc[HIDDEN + col0 + k];
            }
            #pragma unroll
            for (int m = 1; m < 64; m <<= 1) {
                po0 += __shfl_xor(po0, m);
                po1 += __shfl_xor(po1, m);
            }
            if (lane == 0) { outred[wave * 2 + 0] = po0; outred[wave * 2 + 1] = po1; }
        }
        __syncthreads();

        if (wave == 0) {
            const int l = lane & 31;
            float sum = 0.0f;
            #pragma unroll
            for (int ww = 0; ww < 8; ++ww) sum += red[ww * 32 + l];
            const float x0 = pc_sh[2 * s], x1 = pc_sh[2 * s + 1];
            const float gate = sum + bias_r + wi0_r * x0 + wi1_r * x1;
            const float iv = __shfl(gate, (lane & 7));
            const float fv = __shfl(gate, 8 + (lane & 7));
            const float gv = __shfl(gate, 16 + (lane & 7));
            const float ov = __shfl(gate, 24 + (lane & 7));
            const float cnew = sigmoidf_(fv) * creg + sigmoidf_(iv) * tanhf(gv);
            const float hnew = sigmoidf_(ov) * tanhf(cnew);
            creg = cnew;
            const uint32_t hb = __float_as_uint(hnew);
            const uint32_t lo = __shfl(hb, 2 * (lane & 3));
            const uint32_t hi = __shfl(hb, 2 * (lane & 3) + 1);
            if (lane < 4) {
                const uint64_t qv = (uint64_t)lo | ((uint64_t)hi << 32);
                uint64_t* dst = reinterpret_cast<uint64_t*>(
                    hhist + (size_t)(s + 1) * HIDDEN + b * UPW) + lane;
                __hip_atomic_store(dst, qv, __ATOMIC_RELAXED, __HIP_MEMORY_SCOPE_AGENT);
            }
            asm volatile("s_waitcnt vmcnt(0)" ::: "memory");
            if (lane == 0) {
                __hip_atomic_store(flags + (size_t)b * FLAG_STRIDE, s + 1,
                                   __ATOMIC_RELAXED, __HIP_MEMORY_SCOPE_AGENT);
            }
        }
        if (rot && t == 64) {
            float o0 = 0.0f, o1 = 0.0f;
            #pragma unroll
            for (int ww = 0; ww < 8; ++ww) { o0 += outred[ww * 2]; o1 += outred[ww * 2 + 1]; }
            out[(s - 1) * 2 + 0] = 0.25f * o0 + b_fc[0];
            out[(s - 1) * 2 + 1] = 0.25f * o1 + b_fc[1];
        }
        if (watcher) {
            const int l4 = lane * 4;
            const int* f0p = flags + (size_t)(l4 + 0) * FLAG_STRIDE;
            const int* f1p = flags + (size_t)(l4 + 1) * FLAG_STRIDE;
            const int* f2p = flags + (size_t)(l4 + 2) * FLAG_STRIDE;
            const int* f3p = flags + (size_t)(l4 + 3) * FLAG_STRIDE;
            for (;;) {
                const int f0 = __hip_atomic_load(f0p, __ATOMIC_RELAXED, __HIP_MEMORY_SCOPE_AGENT);
                const int f1 = __hip_atomic_load(f1p, __ATOMIC_RELAXED, __HIP_MEMORY_SCOPE_AGENT);
                const int f2 = __hip_atomic_load(f2p, __ATOMIC_RELAXED, __HIP_MEMORY_SCOPE_AGENT);
                const int f3 = __hip_atomic_load(f3p, __ATOMIC_RELAXED, __HIP_MEMORY_SCOPE_AGENT);
                const bool ok = (f0 >= s + 1) & (f1 >= s + 1) & (f2 >= s + 1) & (f3 >= s + 1);
                if (__all(ok)) break;
            }
            __hip_atomic_store(go + (size_t)lane * GO_STRIDE, s + 1,
                               __ATOMIC_RELAXED, __HIP_MEMORY_SCOPE_AGENT);
        }
        if (t == 0 && b != NWG - 1) {
            const int* gop = go + (size_t)(b >> 2) * GO_STRIDE;
            while (__hip_atomic_load(gop, __ATOMIC_RELAXED,
                                     __HIP_MEMORY_SCOPE_AGENT) < s + 1) {}
        }
        __syncthreads();
    }

    if (b == ((TSTEPS - 1) & 255)) {
        const float* hsrc = hhist + (size_t)TSTEPS * HIDDEN;
        float po0 = 0.0f, po1 = 0.0f;
        #pragma unroll
        for (int k = 0; k < CPT; ++k) {
            const float hv = hsrc[col0 + k];
            po0 += hv * W_fc[col0 + k];
            po1 += hv * W_fc[HIDDEN + col0 + k];
        }
        #pragma unroll
        for (int m = 1; m < 64; m <<= 1) {
            po0 += __shfl_xor(po0, m);
            po1 += __shfl_xor(po1, m);
        }
        if (lane == 0) { outred[wave * 2 + 0] = po0; outred[wave * 2 + 1] = po1; }
        __syncthreads();
        if (t == 0) {
            float o0 = 0.0f, o1 = 0.0f;
            #pragma unroll
            for (int ww = 0; ww < 8; ++ww) { o0 += outred[ww * 2]; o1 += outred[ww * 2 + 1]; }
            out[(TSTEPS - 1) * 2 + 0] = 0.25f * o0 + b_fc[0];
            out[(TSTEPS - 1) * 2 + 1] = 0.25f * o1 + b_fc[1];
        }
    }
}

extern "C" void kernel_launch(void* const* d_in, const int* in_sizes, int n_in,
                              void* d_out, int out_size, void* d_ws, size_t ws_size,
                              hipStream_t stream) {
    const float* features = (const float*)d_in[0];
    const float* pc       = (const float*)d_in[1];
    const float* W_ih     = (const float*)d_in[2];
    const float* W_hh     = (const float*)d_in[3];
    const float* b_ih     = (const float*)d_in[4];
    const float* b_hh     = (const float*)d_in[5];
    const float* W_fc     = (const float*)d_in[6];
    const float* b_fc     = (const float*)d_in[7];
    float* out = (float*)d_out;

    const size_t go_bytes = (size_t)64 * GO_STRIDE * sizeof(int);                    // 8 KB
    const size_t hh_bytes = (size_t)(TSTEPS + 1) * STEP_QW * sizeof(uint64_t);       // ~12.6 MB
    const size_t need_v8  = go_bytes + hh_bytes;

    if (ws_size >= need_v8) {
        int*      go = (int*)d_ws;
        uint64_t* hh = (uint64_t*)((char*)d_ws + go_bytes);
        // tags/go must be cleared every call: prevents cross-replay stale-tag
        // validation (which would let the recurrence free-run on leftover data)
        hipMemsetAsync(d_ws, 0, need_v8, stream);
        hipLaunchKernelGGL(lstm_v8, dim3(NWG), dim3(TPB), 0, stream,
                           features, pc, W_ih, W_hh, b_ih, b_hh, W_fc, b_fc,
                           out, go, hh);
    } else {
        const size_t flags_bytes = (size_t)NWG * FLAG_STRIDE * sizeof(int);  // 32 KB
        const size_t hh_off      = flags_bytes + go_bytes;                   // 40 KB
        int*   flags = (int*)d_ws;
        int*   go    = (int*)((char*)d_ws + flags_bytes);
        float* hhist = (float*)((char*)d_ws + hh_off);
        hipMemsetAsync(d_ws, 0, hh_off, stream);
        hipLaunchKernelGGL(lstm_v6, dim3(NWG), dim3(TPB), 0, stream,
                           features, pc, W_ih, W_hh, b_ih, b_hh, W_fc, b_fc,
                           out, flags, go, hhist);
    }
}